// Round 4
// baseline (490.149 us; speedup 1.0000x reference)
//
#include <hip/hip_runtime.h>

#define D_H 32
#define NREP 32
#define DEGCAP 131072   // 1024 chunks * 128, >= N+1, zero-padded for int4 sums

// ---------------- CSR build ----------------

__global__ void k_hist(const int* __restrict__ dst, int* __restrict__ deg, int E) {
    int e = blockIdx.x * blockDim.x + threadIdx.x;
    if (e < E) atomicAdd(&deg[dst[e]], 1);
}

// One block, 1024 threads. Thread c sums deg[c*128 .. c*128+127] (zero-padded),
// then block-wide exclusive scan -> chunkOff[1024].
__global__ void k_scanA(const int* __restrict__ deg, int* __restrict__ chunkOff) {
    __shared__ int sh[1024];
    int c = threadIdx.x;
    const int4* p = (const int4*)(deg + c * 128);
    int s = 0;
#pragma unroll
    for (int q = 0; q < 32; ++q) { int4 v = p[q]; s += v.x + v.y + v.z + v.w; }
    sh[c] = s;
    __syncthreads();
    for (int off = 1; off < 1024; off <<= 1) {
        int v = (c >= off) ? sh[c - off] : 0;
        __syncthreads();
        sh[c] += v;
        __syncthreads();
    }
    chunkOff[c] = (c == 0) ? 0 : sh[c - 1];
}

// Block c scans its 128-entry chunk; offs[i] = chunkOff[c] + exclusive(i).
// Also writes offs[N] = E (at i == N).
__global__ void k_scanB(const int* __restrict__ deg, const int* __restrict__ chunkOff,
                        int* __restrict__ offs, int N) {
    __shared__ int sh[128];
    int c = blockIdx.x, t = threadIdx.x;
    int i = c * 128 + t;
    int val = (i < N) ? deg[i] : 0;
    sh[t] = val;
    __syncthreads();
    for (int off = 1; off < 128; off <<= 1) {
        int v = (t >= off) ? sh[t - off] : 0;
        __syncthreads();
        sh[t] += v;
        __syncthreads();
    }
    if (i <= N) offs[i] = chunkOff[c] + sh[t] - val;
}

__global__ void k_fill(const int* __restrict__ src, const int* __restrict__ dst,
                       int* __restrict__ cursor, int* __restrict__ csr, int E) {
    int e = blockIdx.x * blockDim.x + threadIdx.x;
    if (e < E) {
        int pos = atomicAdd(&cursor[dst[e]], 1);
        csr[pos] = src[e];
    }
}

// ---------------- node projections ----------------

// Fused input-net + projection (iter 0). One thread per node; weights at
// wave-uniform indices -> scalar loads. A = (f@W1^T + b_c) - f@W2^T, B = f@W2^T.
__global__ void k_ab0(const float* __restrict__ x, const float* __restrict__ W_in,
                      const float* __restrict__ b_in, const float* __restrict__ W_c,
                      const float* __restrict__ b_c, float* __restrict__ A,
                      float* __restrict__ B, int N) {
    int n = blockIdx.x * blockDim.x + threadIdx.x;
    if (n >= N) return;
    float f[48];
    const float4* xr = (const float4*)(x + (size_t)n * 16);
#pragma unroll
    for (int q = 0; q < 4; ++q) {
        float4 v = xr[q];
        f[32 + 4 * q] = v.x; f[33 + 4 * q] = v.y;
        f[34 + 4 * q] = v.z; f[35 + 4 * q] = v.w;
    }
#pragma unroll
    for (int j = 0; j < 32; ++j) {
        const float* w = W_in + j * 16;
        float acc = b_in[j];
#pragma unroll
        for (int i = 0; i < 16; ++i) acc += f[32 + i] * w[i];
        f[j] = tanhf(acc);
    }
#pragma unroll 4
    for (int j = 0; j < 32; ++j) {
        const float* w = W_c + j * 96;
        float p = b_c[j];
        float bb = 0.f;
#pragma unroll
        for (int i = 0; i < 48; ++i) {
            p  += f[i] * w[i];
            bb += f[i] * w[48 + i];
        }
        A[(size_t)n * D_H + j] = p - bb;
        B[(size_t)n * D_H + j] = bb;
    }
}

// Projection for iter 1: feats = [H, x].
__global__ void k_ab1(const float* __restrict__ H, const float* __restrict__ x,
                      const float* __restrict__ W_c, const float* __restrict__ b_c,
                      float* __restrict__ A, float* __restrict__ B, int N) {
    int n = blockIdx.x * blockDim.x + threadIdx.x;
    if (n >= N) return;
    float f[48];
    const float4* hr = (const float4*)(H + (size_t)n * D_H);
#pragma unroll
    for (int q = 0; q < 8; ++q) {
        float4 v = hr[q];
        f[4 * q]     = v.x; f[4 * q + 1] = v.y;
        f[4 * q + 2] = v.z; f[4 * q + 3] = v.w;
    }
    const float4* xr = (const float4*)(x + (size_t)n * 16);
#pragma unroll
    for (int q = 0; q < 4; ++q) {
        float4 v = xr[q];
        f[32 + 4 * q] = v.x; f[33 + 4 * q] = v.y;
        f[34 + 4 * q] = v.z; f[35 + 4 * q] = v.w;
    }
#pragma unroll 4
    for (int j = 0; j < 32; ++j) {
        const float* w = W_c + j * 96;
        float p = b_c[j];
        float bb = 0.f;
#pragma unroll
        for (int i = 0; i < 48; ++i) {
            p  += f[i] * w[i];
            bb += f[i] * w[48 + i];
        }
        A[(size_t)n * D_H + j] = p - bb;
        B[(size_t)n * D_H + j] = bb;
    }
}

// ---------------- edge passes ----------------

__device__ __forceinline__ float sigm(float v) {
    return 1.f / (1.f + __expf(-v));
}

// CSR path, iter 0: H[d] = sum over d's in-edges of sigmoid(A[d] + B[src]).
// 32 lanes per node, 8 nodes per 256-thread block. No atomics.
__global__ void k_gedge1(const int* __restrict__ offs, const int* __restrict__ csr,
                         const float* __restrict__ A, const float* __restrict__ B,
                         float* __restrict__ H, int N) {
    int d = blockIdx.x * 8 + (threadIdx.x >> 5);
    int k = threadIdx.x & 31;
    if (d >= N) return;
    int p0 = offs[d], p1 = offs[d + 1];
    float a = A[(size_t)d * D_H + k];
    float acc = 0.f;
    int p = p0;
    for (; p + 2 <= p1; p += 2) {
        int s0 = csr[p], s1 = csr[p + 1];
        float v0 = a + B[(size_t)s0 * D_H + k];
        float v1 = a + B[(size_t)s1 * D_H + k];
        acc += sigm(v0) + sigm(v1);
    }
    if (p < p1) {
        int s = csr[p];
        acc += sigm(a + B[(size_t)s * D_H + k]);
    }
    H[(size_t)d * D_H + k] = acc;
}

// CSR path, iter 1 fused with global mean.
__global__ void k_gedge2(const int* __restrict__ offs, const int* __restrict__ csr,
                         const float* __restrict__ A, const float* __restrict__ B,
                         float* __restrict__ Srep, int N) {
    int slot = threadIdx.x >> 5;
    int k = threadIdx.x & 31;
    float acc = 0.f;
    for (int d = blockIdx.x * 8 + slot; d < N; d += gridDim.x * 8) {
        int p0 = offs[d], p1 = offs[d + 1];
        float a = A[(size_t)d * D_H + k];
        int p = p0;
        for (; p + 2 <= p1; p += 2) {
            int s0 = csr[p], s1 = csr[p + 1];
            float v0 = a + B[(size_t)s0 * D_H + k];
            float v1 = a + B[(size_t)s1 * D_H + k];
            acc += sigm(v0) + sigm(v1);
        }
        if (p < p1) {
            int s = csr[p];
            acc += sigm(a + B[(size_t)s * D_H + k]);
        }
    }
    __shared__ float red[8][32];
    red[slot][k] = acc;
    __syncthreads();
    if (threadIdx.x < 32) {
        float s = 0.f;
#pragma unroll
        for (int r = 0; r < 8; ++r) s += red[r][threadIdx.x];
        unsafeAtomicAdd(&Srep[(blockIdx.x & (NREP - 1)) * D_H + threadIdx.x], s);
    }
}

// Fallback (R2-proven) scatter path, iter 0.
__global__ void k_edge1(const int* __restrict__ src, const int* __restrict__ dst,
                        const float* __restrict__ A, const float* __restrict__ B,
                        float* __restrict__ Hacc, int E) {
    int t = blockIdx.x * blockDim.x + threadIdx.x;
    int e = t >> 5;
    int k = t & 31;
    if (e >= E) return;
    int d = dst[e];
    int s = src[e];
    float v = A[(size_t)d * D_H + k] + B[(size_t)s * D_H + k];
    unsafeAtomicAdd(&Hacc[(size_t)d * D_H + k], sigm(v));
}

// Fallback scatter path, iter 1 fused with global mean (edge-strided).
__global__ void k_edge2(const int* __restrict__ src, const int* __restrict__ dst,
                        const float* __restrict__ A, const float* __restrict__ B,
                        float* __restrict__ Srep, int E) {
    int k = threadIdx.x & 31;
    int slot = threadIdx.x >> 5;
    int e0 = blockIdx.x * 8 + slot;
    int stride = gridDim.x * 8;
    float acc = 0.f;
    for (int e = e0; e < E; e += stride) {
        int d = dst[e];
        int s = src[e];
        acc += sigm(A[(size_t)d * D_H + k] + B[(size_t)s * D_H + k]);
    }
    __shared__ float red[8][32];
    red[slot][k] = acc;
    __syncthreads();
    if (threadIdx.x < 32) {
        float s = 0.f;
#pragma unroll
        for (int r = 0; r < 8; ++r) s += red[r][threadIdx.x];
        unsafeAtomicAdd(&Srep[(blockIdx.x & (NREP - 1)) * D_H + threadIdx.x], s);
    }
}

// out = sigmoid(W_out . (S/N) + b_out), S = sum over replicas.
__global__ void k_final(const float* __restrict__ Srep, const float* __restrict__ W_out,
                        const float* __restrict__ b_out, float* __restrict__ out,
                        float invN) {
    int j = threadIdx.x;  // 0..63
    float v = 0.f;
    if (j < 32) {
        float s = 0.f;
#pragma unroll
        for (int r = 0; r < NREP; ++r) s += Srep[r * D_H + j];
        v = s * invN * W_out[j];
    }
#pragma unroll
    for (int off = 32; off > 0; off >>= 1) v += __shfl_down(v, off);
    if (j == 0) out[0] = 1.f / (1.f + __expf(-(v + b_out[0])));
}

extern "C" void kernel_launch(void* const* d_in, const int* in_sizes, int n_in,
                              void* d_out, int out_size, void* d_ws, size_t ws_size,
                              hipStream_t stream) {
    const float* x     = (const float*)d_in[0];
    const int*   ei    = (const int*)d_in[1];
    const float* W_in  = (const float*)d_in[2];
    const float* b_in  = (const float*)d_in[3];
    const float* W_c   = (const float*)d_in[4];
    const float* b_c   = (const float*)d_in[5];
    const float* W_out = (const float*)d_in[6];
    const float* b_out = (const float*)d_in[7];

    const int N = in_sizes[0] / 16;
    const int E = in_sizes[1] / 2;
    const int* src = ei;        // edge_index[0]
    const int* dst = ei + E;    // edge_index[1]

    // ---- workspace layout ----
    float* H    = (float*)d_ws;                 // N*32
    float* A    = H + (size_t)N * D_H;          // N*32
    float* B    = A + (size_t)N * D_H;          // N*32
    float* Srep = B + (size_t)N * D_H;          // NREP*32 = 1024
    int* deg      = (int*)(Srep + NREP * D_H);  // DEGCAP (zero-padded, 16B-aligned)
    int* offs     = deg + DEGCAP;               // N+2
    int* chunkOff = offs + (N + 2);             // 1024
    int* cursor   = chunkOff + 1024;            // N
    int* csr      = cursor + N;                 // E

    size_t need_base = ((size_t)3 * N * D_H + NREP * D_H) * 4;
    size_t need_csr  = need_base +
                       ((size_t)DEGCAP + (N + 2) + 1024 + N + E) * 4;
    bool use_csr = ws_size >= need_csr;   // ws_size is constant across calls

    float* out = (float*)d_out;

    if (use_csr) {
        // ---- CSR build (per launch; identical work every call) ----
        hipMemsetAsync(deg, 0, DEGCAP * sizeof(int), stream);
        k_hist<<<(E + 255) / 256, 256, 0, stream>>>(dst, deg, E);
        k_scanA<<<1, 1024, 0, stream>>>(deg, chunkOff);
        k_scanB<<<(N + 128) / 128 + 1, 128, 0, stream>>>(deg, chunkOff, offs, N);
        hipMemcpyAsync(cursor, offs, N * sizeof(int), hipMemcpyDeviceToDevice, stream);
        k_fill<<<(E + 255) / 256, 256, 0, stream>>>(src, dst, cursor, csr, E);

        // ---- Iteration 0 ----
        k_ab0<<<(N + 255) / 256, 256, 0, stream>>>(x, W_in, b_in, W_c, b_c, A, B, N);
        k_gedge1<<<(N + 7) / 8, 256, 0, stream>>>(offs, csr, A, B, H, N);

        // ---- Iteration 1 + global mean ----
        k_ab1<<<(N + 255) / 256, 256, 0, stream>>>(H, x, W_c, b_c, A, B, N);
        hipMemsetAsync(Srep, 0, NREP * D_H * sizeof(float), stream);
        k_gedge2<<<2048, 256, 0, stream>>>(offs, csr, A, B, Srep, N);
    } else {
        // ---- Fallback: R2-proven scatter path (needs only need_base bytes) ----
        k_ab0<<<(N + 255) / 256, 256, 0, stream>>>(x, W_in, b_in, W_c, b_c, A, B, N);
        hipMemsetAsync(H, 0, (size_t)N * D_H * sizeof(float), stream);
        k_edge1<<<(int)(((size_t)E * 32 + 255) / 256), 256, 0, stream>>>(src, dst, A, B, H, E);

        k_ab1<<<(N + 255) / 256, 256, 0, stream>>>(H, x, W_c, b_c, A, B, N);
        hipMemsetAsync(Srep, 0, NREP * D_H * sizeof(float), stream);
        k_edge2<<<2048, 256, 0, stream>>>(src, dst, A, B, Srep, E);
    }

    k_final<<<1, 64, 0, stream>>>(Srep, W_out, b_out, out, 1.f / (float)N);
}